// Round 4
// baseline (344.519 us; speedup 1.0000x reference)
//
#include <hip/hip_runtime.h>
#include <hip/hip_bf16.h>

using f32x4  = __attribute__((ext_vector_type(4))) float;
using bf16x8 = __attribute__((ext_vector_type(8))) short;
using s16x4  = __attribute__((ext_vector_type(4))) short;

#define TT 128
#define BB 256
#define II 512
#define HH 1024
#define MM (TT * BB)

__device__ __forceinline__ short f2bf(float f) {
    unsigned u = __float_as_uint(f);
    u = u + 0x7FFFu + ((u >> 16) & 1u);   // round-nearest-even
    return (short)(u >> 16);
}

__device__ __forceinline__ float sigmoid_f(float x) {
    float e = __expf(-fabsf(x));
    float s = 1.0f / (1.0f + e);
    return x >= 0.0f ? s : 1.0f - s;
}

__device__ __forceinline__ float tanh_f(float x) {
    float e = __expf(-2.0f * fabsf(x));
    float t = (1.0f - e) / (1.0f + e);
    return x >= 0.0f ? t : -t;
}

__device__ __forceinline__ void gload_lds16(const void* g, void* l) {
    __builtin_amdgcn_global_load_lds((const __attribute__((address_space(1))) unsigned*)g,
                                     (__attribute__((address_space(3))) unsigned*)l,
                                     16, 0, 0);
}

// ---- f32 -> bf16 bulk convert for A and W in one launch ----
__global__ __launch_bounds__(256)
void cvt_both_kernel(const float* __restrict__ A, const float* __restrict__ W,
                     short* __restrict__ dst, int nA8, int nTot8) {
    const int stride = gridDim.x * blockDim.x;
    for (int i = blockIdx.x * blockDim.x + threadIdx.x; i < nTot8; i += stride) {
        const float* src = (i < nA8) ? (A + (size_t)i * 8) : (W + (size_t)(i - nA8) * 8);
        f32x4 v0 = ((const f32x4*)src)[0];
        f32x4 v1 = ((const f32x4*)src)[1];
        bf16x8 o;
        o[0] = f2bf(v0.x); o[1] = f2bf(v0.y); o[2] = f2bf(v0.z); o[3] = f2bf(v0.w);
        o[4] = f2bf(v1.x); o[5] = f2bf(v1.y); o[6] = f2bf(v1.z); o[7] = f2bf(v1.w);
        ((bf16x8*)dst)[i] = o;
    }
}

// ---- fused GEMM + GRU epilogue: BM=256, N=192 (3 gates x 64 h), BK=64 ----
// 8 waves (4M x 2N gate-aligned). 8-phase-style schedule: 4 fine phases per
// K-tile {ds_read subtile | 1-2 staging issues -> barrier -> lgkmcnt(0) ->
// setprio+12 MFMA -> barrier}. A double-buffered (32KBx2), W TRIPLE-buffered
// (24KBx3) so W(u+2) issues a full tile early => boundary wait is vmcnt(3)
// with 3 loads always in flight (never drains). LDS = 136KB, 1 block/CU.
__global__ __launch_bounds__(512, 2)
void gru_gemm8p_kernel(const short* __restrict__ Abf,   // (M, I) bf16
                       const short* __restrict__ Wbf,   // (3H, I) bf16
                       const float* __restrict__ bih,
                       const float* __restrict__ bhh,
                       float* __restrict__ out)         // (B, T, H) f32
{
    // A0 @0, A1 @32768 (32KB each) ; W0 @65536, W1 @90112, W2 @114688 (24KB each)
    __shared__ char lds[139264];

    const int tid  = threadIdx.x;
    const int wid  = tid >> 6;
    const int lane = tid & 63;
    const int l15  = lane & 15;
    const int l4   = lane >> 4;
    const int wm   = wid >> 1;    // 0..3 : M quarter (64 rows)
    const int wn   = wid & 1;     // 0..1 : h half (32 cols, all 3 gates)

    // htile-major: blocks sharing an A-tile are 128 apart (128%8==0 -> same XCD)
    const int mtile = blockIdx.x & 127;
    const int htile = blockIdx.x >> 7;
    const int m0 = mtile * 256;
    const int h0 = htile * 64;

    // staging: one gload_lds = 8 rows x 128B; lane -> (sub-row lr8, 16B chunk lc)
    const int lr8 = lane >> 3;
    const int lc  = lane & 7;
    const int csw = (lc * 16) ^ (lr8 << 4);   // pre-swizzled source byte col

    const char* Ab = (const char*)Abf;
    const char* Wb = (const char*)Wbf;

    size_t aAddr[4];
    size_t wAddr[3];
    #pragma unroll
    for (int j = 0; j < 4; ++j)
        aAddr[j] = (size_t)(m0 + (wid * 4 + j) * 8 + lr8) * 1024 + csw;
    #pragma unroll
    for (int j = 0; j < 3; ++j) {
        const int row = (wid * 3 + j) * 8 + lr8;   // 0..191 = g*64 + wr
        const int g   = row >> 6;
        const int wr  = row & 63;
        wAddr[j] = (size_t)(g * HH + h0 + wr) * 1024 + csw;
    }

#define ABUF(p) ((char*)lds + (p) * 32768)
#define WBUF(q) ((char*)lds + 65536 + (q) * 24576)
#define GLA(u1, j) gload_lds16(Ab + aAddr[j] + (size_t)(u1) * 128, \
                               ABUF((u1) & 1) + (wid * 4 + (j)) * 1024)
#define GLW(u2, j) gload_lds16(Wb + wAddr[j] + (size_t)(u2) * 128, \
                               WBUF((u2) % 3) + (wid * 3 + (j)) * 1024)

    f32x4 acc[4][3][2];
    #pragma unroll
    for (int mf = 0; mf < 4; ++mf)
        #pragma unroll
        for (int g = 0; g < 3; ++g)
            #pragma unroll
            for (int nf = 0; nf < 2; ++nf)
                acc[mf][g][nf] = (f32x4){0.f, 0.f, 0.f, 0.f};

    // prologue: W(0), A(0), W(1) -> wait leaves W(1)x3 in flight
    #pragma unroll
    for (int j = 0; j < 3; ++j) GLW(0, j);
    #pragma unroll
    for (int j = 0; j < 4; ++j) GLA(0, j);
    #pragma unroll
    for (int j = 0; j < 3; ++j) GLW(1, j);
    asm volatile("s_waitcnt vmcnt(3)" ::: "memory");
    __builtin_amdgcn_s_barrier();

    const int xsw = (l15 & 7) << 4;

#define PHASE_TAIL(NH)                                                        \
    __builtin_amdgcn_s_barrier();                                             \
    asm volatile("s_waitcnt lgkmcnt(0)" ::: "memory");                        \
    __builtin_amdgcn_sched_barrier(0);                                        \
    __builtin_amdgcn_s_setprio(1);                                            \
    _Pragma("unroll")                                                         \
    for (int mf = 0; mf < 4; ++mf)                                            \
        _Pragma("unroll")                                                     \
        for (int g = 0; g < 3; ++g)                                           \
            acc[mf][g][NH] = __builtin_amdgcn_mfma_f32_16x16x32_bf16(         \
                a[mf], b[g], acc[mf][g][NH], 0, 0, 0);                        \
    __builtin_amdgcn_s_setprio(0);

    #pragma unroll
    for (int u = 0; u < 8; ++u) {
        const char* Al = ABUF(u & 1);
        const char* Wl = WBUF(u % 3);
        bf16x8 a[4], b[3];

        // ---- P0: (k0, nh0) : 4 A-reads + 3 B-reads, issue 2 A(u+1) ----
        #pragma unroll
        for (int mf = 0; mf < 4; ++mf)
            a[mf] = *(const bf16x8*)(Al + (wm * 64 + mf * 16 + l15) * 128 + ((l4 * 16) ^ xsw));
        #pragma unroll
        for (int g = 0; g < 3; ++g)
            b[g] = *(const bf16x8*)(Wl + (g * 64 + wn * 32 + l15) * 128 + ((l4 * 16) ^ xsw));
        if (u < 7) { GLA(u + 1, 0); GLA(u + 1, 1); }
        PHASE_TAIL(0)
        __builtin_amdgcn_s_barrier();

        // ---- P1: (k0, nh1) : 3 B-reads (a reuse), issue 2 A(u+1) + 1 W(u+2) ----
        #pragma unroll
        for (int g = 0; g < 3; ++g)
            b[g] = *(const bf16x8*)(Wl + (g * 64 + wn * 32 + 16 + l15) * 128 + ((l4 * 16) ^ xsw));
        if (u < 7) { GLA(u + 1, 2); GLA(u + 1, 3); }
        if (u < 6) { GLW(u + 2, 0); }
        PHASE_TAIL(1)
        __builtin_amdgcn_s_barrier();

        // ---- P2: (k1, nh0) : 4 A-reads + 3 B-reads, issue 1 W(u+2) ----
        #pragma unroll
        for (int mf = 0; mf < 4; ++mf)
            a[mf] = *(const bf16x8*)(Al + (wm * 64 + mf * 16 + l15) * 128 + ((64 + l4 * 16) ^ xsw));
        #pragma unroll
        for (int g = 0; g < 3; ++g)
            b[g] = *(const bf16x8*)(Wl + (g * 64 + wn * 32 + l15) * 128 + ((64 + l4 * 16) ^ xsw));
        if (u < 6) { GLW(u + 2, 1); }
        PHASE_TAIL(0)
        __builtin_amdgcn_s_barrier();

        // ---- P3: (k1, nh1) : 3 B-reads, issue 1 W(u+2), boundary wait ----
        #pragma unroll
        for (int g = 0; g < 3; ++g)
            b[g] = *(const bf16x8*)(Wl + (g * 64 + wn * 32 + 16 + l15) * 128 + ((64 + l4 * 16) ^ xsw));
        if (u < 6) { GLW(u + 2, 2); }
        PHASE_TAIL(1)
        if (u < 6)      asm volatile("s_waitcnt vmcnt(3)" ::: "memory");   // 3 W in flight
        else if (u == 6) asm volatile("s_waitcnt vmcnt(0)" ::: "memory");  // last-tile drain
        __builtin_amdgcn_s_barrier();
    }
#undef PHASE_TAIL
#undef GLA
#undef GLW
#undef ABUF
#undef WBUF

    // ---- fused GRU epilogue + transposed store ----
    // acc[mf][0][nf]=r-gate, [1]=z, [2]=n at identical (row,col) per lane/reg
    #pragma unroll
    for (int nf = 0; nf < 2; ++nf) {
        const int h = h0 + wn * 32 + nf * 16 + l15;
        const float bir = bih[h]          + bhh[h];
        const float biz = bih[HH + h]     + bhh[HH + h];
        const float bin = bih[2 * HH + h];
        const float bhn = bhh[2 * HH + h];
        #pragma unroll
        for (int mf = 0; mf < 4; ++mf) {
            const f32x4 ra = acc[mf][0][nf];
            const f32x4 za = acc[mf][1][nf];
            const f32x4 na = acc[mf][2][nf];
            #pragma unroll
            for (int j = 0; j < 4; ++j) {
                const int m = m0 + wm * 64 + mf * 16 + l4 * 4 + j;
                const int tt = m >> 8;         // B = 256
                const int bb = m & 255;
                const float r = sigmoid_f(ra[j] + bir);
                const float z = sigmoid_f(za[j] + biz);
                const float n = tanh_f(na[j] + bin + r * bhn);
                out[(size_t)bb * (TT * HH) + (size_t)tt * HH + h] = (1.0f - z) * n;
            }
        }
    }
}

// ---- fallback (f32 loads + in-kernel conversion), used only if ws too small ----
__global__ __launch_bounds__(256, 2)
void gru_fused_kernel(const float* __restrict__ A,
                      const float* __restrict__ Wih,
                      const float* __restrict__ bih,
                      const float* __restrict__ bhh,
                      float* __restrict__ out)
{
    __shared__ short As[128 * 64];
    __shared__ short Ws[192 * 64];

    const int tid  = threadIdx.x;
    const int wid  = tid >> 6;
    const int lane = tid & 63;
    const int l15  = lane & 15;
    const int l4   = lane >> 4;

    const int mtile = blockIdx.x >> 4;
    const int htile = blockIdx.x & 15;
    const int m0 = mtile * 128;
    const int h0 = htile * 64;

    const int rbase = tid >> 4;
    const int c4    = tid & 15;
    const int swz   = (rbase & 7) << 3;

    f32x4 acc[2][12];
    #pragma unroll
    for (int i = 0; i < 2; ++i)
        #pragma unroll
        for (int j = 0; j < 12; ++j)
            acc[i][j] = (f32x4){0.f, 0.f, 0.f, 0.f};

    for (int kt = 0; kt < II / 64; ++kt) {
        const int k0 = kt * 64;
        __syncthreads();
        const float* Abp = A + (size_t)(m0 + rbase) * II + k0 + c4 * 4;
        #pragma unroll
        for (int i = 0; i < 8; ++i) {
            f32x4 v = *(const f32x4*)(Abp + (size_t)i * 16 * II);
            s16x4 hv;
            hv.x = f2bf(v.x); hv.y = f2bf(v.y); hv.z = f2bf(v.z); hv.w = f2bf(v.w);
            *(s16x4*)(As + (i * 16 + rbase) * 64 + ((c4 * 4) ^ swz)) = hv;
        }
        #pragma unroll
        for (int i = 0; i < 12; ++i) {
            const int row = i * 16 + rbase;
            const int g   = row >> 6;
            const int r   = row & 63;
            f32x4 v = *(const f32x4*)(Wih + (size_t)(g * HH + h0 + r) * II + k0 + c4 * 4);
            s16x4 hv;
            hv.x = f2bf(v.x); hv.y = f2bf(v.y); hv.z = f2bf(v.z); hv.w = f2bf(v.w);
            *(s16x4*)(Ws + row * 64 + ((c4 * 4) ^ swz)) = hv;
        }
        __syncthreads();

        #pragma unroll
        for (int kk = 0; kk < 2; ++kk) {
            const int kc = kk * 32 + l4 * 8;
            const int r0 = wid * 32 + l15;
            bf16x8 a0 = *(const bf16x8*)(As + r0 * 64 + (kc ^ ((r0 & 7) << 3)));
            bf16x8 a1 = *(const bf16x8*)(As + (r0 + 16) * 64 + (kc ^ ((r0 & 7) << 3)));
            #pragma unroll
            for (int nf = 0; nf < 12; ++nf) {
                const int rn = nf * 16 + l15;
                bf16x8 b = *(const bf16x8*)(Ws + rn * 64 + (kc ^ ((rn & 7) << 3)));
                acc[0][nf] = __builtin_amdgcn_mfma_f32_16x16x32_bf16(a0, b, acc[0][nf], 0, 0, 0);
                acc[1][nf] = __builtin_amdgcn_mfma_f32_16x16x32_bf16(a1, b, acc[1][nf], 0, 0, 0);
            }
        }
    }

    #pragma unroll
    for (int nf = 0; nf < 4; ++nf) {
        const int h = h0 + nf * 16 + l15;
        const float bir = bih[h]          + bhh[h];
        const float biz = bih[HH + h]     + bhh[HH + h];
        const float bin = bih[2 * HH + h];
        const float bhn = bhh[2 * HH + h];
        #pragma unroll
        for (int mf = 0; mf < 2; ++mf) {
            const f32x4 ra = acc[mf][nf];
            const f32x4 za = acc[mf][nf + 4];
            const f32x4 na = acc[mf][nf + 8];
            #pragma unroll
            for (int j = 0; j < 4; ++j) {
                const int m = m0 + wid * 32 + mf * 16 + l4 * 4 + j;
                const int tt = m >> 8;
                const int bb = m & 255;
                const float r = sigmoid_f(ra[j] + bir);
                const float z = sigmoid_f(za[j] + biz);
                const float n = tanh_f(na[j] + bin + r * bhn);
                out[(size_t)bb * (TT * HH) + (size_t)tt * HH + h] = (1.0f - z) * n;
            }
        }
    }
}

extern "C" void kernel_launch(void* const* d_in, const int* in_sizes, int n_in,
                              void* d_out, int out_size, void* d_ws, size_t ws_size,
                              hipStream_t stream) {
    const float* input = (const float*)d_in[0];   // (T,B,I)
    const float* Wih   = (const float*)d_in[1];   // (3H,I)
    // d_in[2] = W_hh: unused (h0 == 0)
    const float* bih   = (const float*)d_in[3];
    const float* bhh   = (const float*)d_in[4];
    float* out = (float*)d_out;

    const size_t nA = (size_t)MM * II;          // 16.78M elems
    const size_t nW = (size_t)3 * HH * II;      // 1.57M elems
    const size_t need = (nA + nW) * sizeof(short);

    if (ws_size >= need) {
        short* Abf = (short*)d_ws;               // W follows A contiguously
        cvt_both_kernel<<<4096, 256, 0, stream>>>(input, Wih, Abf,
                                                  (int)(nA / 8), (int)((nA + nW) / 8));
        const int nblocks = (MM / 256) * (HH / 64);   // 128 mtiles * 16 htiles = 2048
        gru_gemm8p_kernel<<<nblocks, 512, 0, stream>>>(Abf, Abf + nA, bih, bhh, out);
    } else {
        const int nblocks = (MM / 128) * (HH / 64);   // 4096
        gru_fused_kernel<<<nblocks, 256, 0, stream>>>(input, Wih, bih, bhh, out);
    }
}

// Round 5
// 338.493 us; speedup vs baseline: 1.0178x; 1.0178x over previous
//
#include <hip/hip_runtime.h>
#include <hip/hip_bf16.h>

using f32x4  = __attribute__((ext_vector_type(4))) float;
using bf16x8 = __attribute__((ext_vector_type(8))) short;
using s16x4  = __attribute__((ext_vector_type(4))) short;

#define TT 128
#define BB 256
#define II 512
#define HH 1024
#define MM (TT * BB)

__device__ __forceinline__ short f2bf(float f) {
    unsigned u = __float_as_uint(f);
    u = u + 0x7FFFu + ((u >> 16) & 1u);   // round-nearest-even
    return (short)(u >> 16);
}

__device__ __forceinline__ float sigmoid_f(float x) {
    float e = __expf(-fabsf(x));
    float s = 1.0f / (1.0f + e);
    return x >= 0.0f ? s : 1.0f - s;
}

__device__ __forceinline__ float tanh_f(float x) {
    float e = __expf(-2.0f * fabsf(x));
    float t = (1.0f - e) / (1.0f + e);
    return x >= 0.0f ? t : -t;
}

__device__ __forceinline__ void gload_lds16(const void* g, void* l) {
    __builtin_amdgcn_global_load_lds((const __attribute__((address_space(1))) unsigned*)g,
                                     (__attribute__((address_space(3))) unsigned*)l,
                                     16, 0, 0);
}

// ---- f32 -> bf16 bulk convert for A and W in one launch ----
__global__ __launch_bounds__(256)
void cvt_both_kernel(const float* __restrict__ A, const float* __restrict__ W,
                     short* __restrict__ dst, int nA8, int nTot8) {
    const int stride = gridDim.x * blockDim.x;
    for (int i = blockIdx.x * blockDim.x + threadIdx.x; i < nTot8; i += stride) {
        const float* src = (i < nA8) ? (A + (size_t)i * 8) : (W + (size_t)(i - nA8) * 8);
        f32x4 v0 = ((const f32x4*)src)[0];
        f32x4 v1 = ((const f32x4*)src)[1];
        bf16x8 o;
        o[0] = f2bf(v0.x); o[1] = f2bf(v0.y); o[2] = f2bf(v0.z); o[3] = f2bf(v0.w);
        o[4] = f2bf(v1.x); o[5] = f2bf(v1.y); o[6] = f2bf(v1.z); o[7] = f2bf(v1.w);
        ((bf16x8*)dst)[i] = o;
    }
}

// ---- fused GEMM + GRU epilogue: BM=128, N=192 (3 gates x 64 h), BK=64 ----
// R2's proven MFMA loop + full LDS double-buffer (80KB -> 2 blocks/CU) +
// counted s_waitcnt vmcnt(10): tile t+1's 10 loads/wave issue before waiting
// on tile t's; loads stay in flight through the MFMAs (no drain in main loop).
// Raw s_barrier (no implicit vmcnt(0)); sched_barrier(0) pins phase regions.
__global__ __launch_bounds__(256, 2)
void gru_gemm_db_kernel(const short* __restrict__ Abf,   // (M, I) bf16
                        const short* __restrict__ Wbf,   // (3H, I) bf16
                        const float* __restrict__ bih,
                        const float* __restrict__ bhh,
                        float* __restrict__ out)         // (B, T, H) f32
{
    // A0 @0, A1 @16384 (16KB each) ; W0 @32768, W1 @57344 (24KB each) = 80KB
    __shared__ char lds[81920];

    const int tid  = threadIdx.x;
    const int wid  = tid >> 6;
    const int lane = tid & 63;
    const int l15  = lane & 15;
    const int l4   = lane >> 4;

    // htile-major: blocks sharing an A-tile are 256 apart (256%8==0 -> same XCD)
    const int mtile = blockIdx.x & 255;
    const int htile = blockIdx.x >> 8;
    const int m0 = mtile * 128;
    const int h0 = htile * 64;

    // staging: one gload_lds = 8 rows x 128B; lane -> (sub-row lr8, 16B chunk lc)
    const int lr8 = lane >> 3;
    const int lc  = lane & 7;
    const int csw = (lc * 16) ^ (lr8 << 4);   // pre-swizzled source byte col

    const char* Ab = (const char*)Abf;
    const char* Wb = (const char*)Wbf;

    size_t aAddr[4];
    size_t wAddr[6];
    #pragma unroll
    for (int j = 0; j < 4; ++j)
        aAddr[j] = (size_t)(m0 + (wid * 4 + j) * 8 + lr8) * 1024 + csw;
    #pragma unroll
    for (int j = 0; j < 6; ++j) {
        const int row = (wid * 6 + j) * 8 + lr8;   // 0..191 = g*64 + wr
        const int g   = row >> 6;
        const int wr  = row & 63;
        wAddr[j] = (size_t)(g * HH + h0 + wr) * 1024 + csw;
    }

    // 10 gload_lds per wave per K-step (4 A + 6 W)
#define STAGE(t, p)                                                           \
    do {                                                                      \
        const int kb_ = (t) * 128;                                            \
        _Pragma("unroll")                                                     \
        for (int j = 0; j < 4; ++j)                                           \
            gload_lds16(Ab + aAddr[j] + kb_,                                  \
                        lds + (p) * 16384 + (wid * 4 + j) * 1024);            \
        _Pragma("unroll")                                                     \
        for (int j = 0; j < 6; ++j)                                           \
            gload_lds16(Wb + wAddr[j] + kb_,                                  \
                        lds + 32768 + (p) * 24576 + (wid * 6 + j) * 1024);    \
    } while (0)

    f32x4 acc[2][12];
    #pragma unroll
    for (int i = 0; i < 2; ++i)
        #pragma unroll
        for (int j = 0; j < 12; ++j)
            acc[i][j] = (f32x4){0.f, 0.f, 0.f, 0.f};

    STAGE(0, 0);

    const int xsw = (l15 & 7) << 4;

    #pragma unroll
    for (int t = 0; t < 8; ++t) {
        const int p = t & 1;
        if (t < 7) {
            STAGE(t + 1, p ^ 1);                               // 10 more in flight
            asm volatile("s_waitcnt vmcnt(10)" ::: "memory");  // tile t landed
        } else {
            asm volatile("s_waitcnt vmcnt(0)" ::: "memory");
        }
        __builtin_amdgcn_s_barrier();
        __builtin_amdgcn_sched_barrier(0);

        const char* Al = lds + p * 16384;
        const char* Wl = lds + 32768 + p * 24576;

        #pragma unroll
        for (int kk = 0; kk < 2; ++kk) {
            const int cb = kk * 64 + l4 * 16;
            const int r0 = wid * 32 + l15;
            bf16x8 a0 = *(const bf16x8*)(Al + r0 * 128 + (cb ^ xsw));
            bf16x8 a1 = *(const bf16x8*)(Al + (r0 + 16) * 128 + (cb ^ xsw));
            #pragma unroll
            for (int nf = 0; nf < 12; ++nf) {
                const int rn = nf * 16 + l15;
                bf16x8 b = *(const bf16x8*)(Wl + rn * 128 + (cb ^ xsw));
                acc[0][nf] = __builtin_amdgcn_mfma_f32_16x16x32_bf16(a0, b, acc[0][nf], 0, 0, 0);
                acc[1][nf] = __builtin_amdgcn_mfma_f32_16x16x32_bf16(a1, b, acc[1][nf], 0, 0, 0);
            }
        }
        __builtin_amdgcn_sched_barrier(0);   // nothing (incl. next STAGE) crosses up
        __builtin_amdgcn_s_barrier();        // all waves done reading buf p
    }
#undef STAGE

    // ---- fused GRU epilogue + transposed store ----
    // frag nf: gate r; nf+4: gate z; nf+8: gate n -- same lane/reg = same (row,col)
    #pragma unroll
    for (int nf = 0; nf < 4; ++nf) {
        const int h = h0 + nf * 16 + l15;
        const float bir = bih[h]          + bhh[h];
        const float biz = bih[HH + h]     + bhh[HH + h];
        const float bin = bih[2 * HH + h];
        const float bhn = bhh[2 * HH + h];
        #pragma unroll
        for (int mf = 0; mf < 2; ++mf) {
            const f32x4 ra = acc[mf][nf];
            const f32x4 za = acc[mf][nf + 4];
            const f32x4 na = acc[mf][nf + 8];
            #pragma unroll
            for (int j = 0; j < 4; ++j) {
                const int m = m0 + wid * 32 + mf * 16 + l4 * 4 + j;
                const int tt = m >> 8;         // B = 256
                const int bb = m & 255;
                const float r = sigmoid_f(ra[j] + bir);
                const float z = sigmoid_f(za[j] + biz);
                const float n = tanh_f(na[j] + bin + r * bhn);
                out[(size_t)bb * (TT * HH) + (size_t)tt * HH + h] = (1.0f - z) * n;
            }
        }
    }
}

// ---- fallback (f32 loads + in-kernel conversion), used only if ws too small ----
__global__ __launch_bounds__(256, 2)
void gru_fused_kernel(const float* __restrict__ A,
                      const float* __restrict__ Wih,
                      const float* __restrict__ bih,
                      const float* __restrict__ bhh,
                      float* __restrict__ out)
{
    __shared__ short As[128 * 64];
    __shared__ short Ws[192 * 64];

    const int tid  = threadIdx.x;
    const int wid  = tid >> 6;
    const int lane = tid & 63;
    const int l15  = lane & 15;
    const int l4   = lane >> 4;

    const int mtile = blockIdx.x >> 4;
    const int htile = blockIdx.x & 15;
    const int m0 = mtile * 128;
    const int h0 = htile * 64;

    const int rbase = tid >> 4;
    const int c4    = tid & 15;
    const int swz   = (rbase & 7) << 3;

    f32x4 acc[2][12];
    #pragma unroll
    for (int i = 0; i < 2; ++i)
        #pragma unroll
        for (int j = 0; j < 12; ++j)
            acc[i][j] = (f32x4){0.f, 0.f, 0.f, 0.f};

    for (int kt = 0; kt < II / 64; ++kt) {
        const int k0 = kt * 64;
        __syncthreads();
        const float* Abp = A + (size_t)(m0 + rbase) * II + k0 + c4 * 4;
        #pragma unroll
        for (int i = 0; i < 8; ++i) {
            f32x4 v = *(const f32x4*)(Abp + (size_t)i * 16 * II);
            s16x4 hv;
            hv.x = f2bf(v.x); hv.y = f2bf(v.y); hv.z = f2bf(v.z); hv.w = f2bf(v.w);
            *(s16x4*)(As + (i * 16 + rbase) * 64 + ((c4 * 4) ^ swz)) = hv;
        }
        #pragma unroll
        for (int i = 0; i < 12; ++i) {
            const int row = i * 16 + rbase;
            const int g   = row >> 6;
            const int r   = row & 63;
            f32x4 v = *(const f32x4*)(Wih + (size_t)(g * HH + h0 + r) * II + k0 + c4 * 4);
            s16x4 hv;
            hv.x = f2bf(v.x); hv.y = f2bf(v.y); hv.z = f2bf(v.z); hv.w = f2bf(v.w);
            *(s16x4*)(Ws + row * 64 + ((c4 * 4) ^ swz)) = hv;
        }
        __syncthreads();

        #pragma unroll
        for (int kk = 0; kk < 2; ++kk) {
            const int kc = kk * 32 + l4 * 8;
            const int r0 = wid * 32 + l15;
            bf16x8 a0 = *(const bf16x8*)(As + r0 * 64 + (kc ^ ((r0 & 7) << 3)));
            bf16x8 a1 = *(const bf16x8*)(As + (r0 + 16) * 64 + (kc ^ ((r0 & 7) << 3)));
            #pragma unroll
            for (int nf = 0; nf < 12; ++nf) {
                const int rn = nf * 16 + l15;
                bf16x8 b = *(const bf16x8*)(Ws + rn * 64 + (kc ^ ((rn & 7) << 3)));
                acc[0][nf] = __builtin_amdgcn_mfma_f32_16x16x32_bf16(a0, b, acc[0][nf], 0, 0, 0);
                acc[1][nf] = __builtin_amdgcn_mfma_f32_16x16x32_bf16(a1, b, acc[1][nf], 0, 0, 0);
            }
        }
    }

    #pragma unroll
    for (int nf = 0; nf < 4; ++nf) {
        const int h = h0 + nf * 16 + l15;
        const float bir = bih[h]          + bhh[h];
        const float biz = bih[HH + h]     + bhh[HH + h];
        const float bin = bih[2 * HH + h];
        const float bhn = bhh[2 * HH + h];
        #pragma unroll
        for (int mf = 0; mf < 2; ++mf) {
            const f32x4 ra = acc[mf][nf];
            const f32x4 za = acc[mf][nf + 4];
            const f32x4 na = acc[mf][nf + 8];
            #pragma unroll
            for (int j = 0; j < 4; ++j) {
                const int m = m0 + wid * 32 + mf * 16 + l4 * 4 + j;
                const int tt = m >> 8;
                const int bb = m & 255;
                const float r = sigmoid_f(ra[j] + bir);
                const float z = sigmoid_f(za[j] + biz);
                const float n = tanh_f(na[j] + bin + r * bhn);
                out[(size_t)bb * (TT * HH) + (size_t)tt * HH + h] = (1.0f - z) * n;
            }
        }
    }
}

extern "C" void kernel_launch(void* const* d_in, const int* in_sizes, int n_in,
                              void* d_out, int out_size, void* d_ws, size_t ws_size,
                              hipStream_t stream) {
    const float* input = (const float*)d_in[0];   // (T,B,I)
    const float* Wih   = (const float*)d_in[1];   // (3H,I)
    // d_in[2] = W_hh: unused (h0 == 0)
    const float* bih   = (const float*)d_in[3];
    const float* bhh   = (const float*)d_in[4];
    float* out = (float*)d_out;

    const size_t nA = (size_t)MM * II;          // 16.78M elems
    const size_t nW = (size_t)3 * HH * II;      // 1.57M elems
    const size_t need = (nA + nW) * sizeof(short);

    if (ws_size >= need) {
        short* Abf = (short*)d_ws;               // W follows A contiguously
        cvt_both_kernel<<<4096, 256, 0, stream>>>(input, Wih, Abf,
                                                  (int)(nA / 8), (int)((nA + nW) / 8));
        const int nblocks = (MM / 128) * (HH / 64);   // 256 mtiles * 16 htiles = 4096
        gru_gemm_db_kernel<<<nblocks, 256, 0, stream>>>(Abf, Abf + nA, bih, bhh, out);
    } else {
        const int nblocks = (MM / 128) * (HH / 64);   // 4096
        gru_fused_kernel<<<nblocks, 256, 0, stream>>>(input, Wih, bih, bhh, out);
    }
}